// Round 6
// baseline (257.777 us; speedup 1.0000x reference)
//
#include <hip/hip_runtime.h>
#include <hip/hip_bf16.h>

#define NSEQ 2048
#define HID 128
#define HEADS 8
#define HD 16
#define SCALE 0.25f
#define SPLIT 8
#define KEYS_PER (NSEQ / SPLIT)   // 256 keys per block
#define OWN_T 8                   // 16-key tiles per wave (parity split of 16)

typedef unsigned short ushort_t;
typedef __attribute__((ext_vector_type(4))) short short4v;   // 4 bf16 (A/B frag, K=16 MFMA)
typedef __attribute__((ext_vector_type(4))) float floatx4;   // C/D frag
typedef __attribute__((ext_vector_type(4))) float f32x4;

__device__ __forceinline__ unsigned pack_bf16x2(float a, float b) {
    __hip_bfloat16 ba = __float2bfloat16(a);
    __hip_bfloat16 bb = __float2bfloat16(b);
    return (unsigned)*(ushort_t*)&ba | ((unsigned)*(ushort_t*)&bb << 16);
}

// ---------------- kernel A: QKV projection ----------------
// grid 768 blocks x 128 threads; blocks [0,256)->Q (scaled bf16 hi/lo split),
// [256,512)->K bf16 rows, [512,768)->V bf16 TRANSPOSED (Vt[j][n]).
__global__ __launch_bounds__(128) void qkv_kernel(
    const float* __restrict__ x, const float* __restrict__ Wq,
    const float* __restrict__ Wk, const float* __restrict__ Wv,
    const float* __restrict__ bq, const float* __restrict__ bk,
    const float* __restrict__ bv,
    __hip_bfloat16* __restrict__ Qh, __hip_bfloat16* __restrict__ Ql,
    __hip_bfloat16* __restrict__ Kb, __hip_bfloat16* __restrict__ Vt)
{
    __shared__ float xs[8 * HID];
    const int j = threadIdx.x;
    const int mat = blockIdx.x >> 8;
    const int rb = blockIdx.x & 255;
    const int r0 = rb * 8;
    const float* W = (mat == 0) ? Wq : (mat == 1) ? Wk : Wv;
    const float* bb = (mat == 0) ? bq : (mat == 1) ? bk : bv;
    const float4* xg = (const float4*)(x + (size_t)r0 * HID);
    float4* xl = (float4*)xs;
    for (int i = j; i < 8 * HID / 4; i += 128) xl[i] = xg[i];
    __syncthreads();
    float acc[8];
#pragma unroll
    for (int r = 0; r < 8; ++r) acc[r] = 0.f;
    const float4* Wrow = (const float4*)(W + (size_t)j * HID);
#pragma unroll 4
    for (int i4 = 0; i4 < HID / 4; ++i4) {
        float4 wv = Wrow[i4];
#pragma unroll
        for (int r = 0; r < 8; ++r) {
            float4 xv = *(const float4*)&xs[r * HID + i4 * 4];
            acc[r] = fmaf(xv.x, wv.x, acc[r]);
            acc[r] = fmaf(xv.y, wv.y, acc[r]);
            acc[r] = fmaf(xv.z, wv.z, acc[r]);
            acc[r] = fmaf(xv.w, wv.w, acc[r]);
        }
    }
    float bv_ = bb[j];
#pragma unroll
    for (int r = 0; r < 8; ++r) acc[r] += bv_;
    if (mat == 0) {
        // scaled hi/lo bf16 split: Qh + Ql represents acc*SCALE to ~2^-17 rel
#pragma unroll
        for (int r = 0; r < 8; ++r) {
            float qsv = acc[r] * SCALE;                 // exact (SCALE = 2^-2)
            __hip_bfloat16 hb = __float2bfloat16(qsv);
            float hf = __bfloat162float(hb);
            __hip_bfloat16 lb = __float2bfloat16(qsv - hf);
            Qh[(size_t)(r0 + r) * HID + j] = hb;
            Ql[(size_t)(r0 + r) * HID + j] = lb;
        }
    } else if (mat == 1) {
#pragma unroll
        for (int r = 0; r < 8; ++r) Kb[(size_t)(r0 + r) * HID + j] = __float2bfloat16(acc[r]);
    } else {
        unsigned u[4];
#pragma unroll
        for (int p = 0; p < 4; ++p) u[p] = pack_bf16x2(acc[2 * p], acc[2 * p + 1]);
        *(uint4*)((ushort_t*)Vt + (size_t)j * NSEQ + r0) = make_uint4(u[0], u[1], u[2], u[3]);
    }
}

// ---------------- kernel B: fused attention, direct-to-fragment bias ----------------
// grid 1024 blocks x 256 threads; block = 16 q-rows x 256 keys, 4 waves:
// wave = (head-half h0 = (wid&1)*4) x (key-tile parity par = wid>>1).
// KEY INSIGHT: for S^T = K.Q^T, lane (qi,g) reg r holds S^T[key=4g+r][q=qi];
// its bias addend bias[n0+qi][m1+4g+r][h0..h0+3] is a lane-PRIVATE 16B vector,
// strided 32B over r -> 4 dwordx4 loads/lane/tile, NO LDS, NO transpose, NO barrier.
// Register double-buffer (1 tile ahead); 16 waves/CU (one exact generation).
__global__ __launch_bounds__(256, 4) void attn_kernel(
    const __hip_bfloat16* __restrict__ Qh, const __hip_bfloat16* __restrict__ Ql,
    const __hip_bfloat16* __restrict__ Kb, const __hip_bfloat16* __restrict__ Vt,
    const float* __restrict__ bias, const unsigned char* __restrict__ mask,
    float* __restrict__ Op, float* __restrict__ Lp)
{
    __shared__ float ob[2][16][64];   // 8 KB: parity-merge O partials
    __shared__ float lr[2][4][16];    // 512 B: parity-merge l partials

    const int t = threadIdx.x;
    const int lane = t & 63;
    const int wid = t >> 6;
    const int qi = lane & 15;          // q row (scores) / d col (PV out)
    const int g = lane >> 4;           // 0..3
    const int h0 = (wid & 1) * 4;      // this wave's 4 heads
    const int par = wid >> 1;          // this wave's key-tile parity

    const int nb = blockIdx.x & 127;
    const int sp = blockIdx.x >> 7;
    const int n0 = nb * 16;
    const int m0 = sp * KEYS_PER;

    // Q B-fragments for 4 heads (hi/lo): B[k=dim 4g+i][col=q=qi]
    short4v qhf[4], qlf[4];
#pragma unroll
    for (int hh = 0; hh < 4; ++hh) {
        const size_t qoff = (size_t)(n0 + qi) * HID + (h0 + hh) * HD + 4 * g;
        qhf[hh] = *(const short4v*)((const ushort_t*)Qh + qoff);
        qlf[hh] = *(const short4v*)((const ushort_t*)Ql + qoff);
    }

    floatx4 o[4];
    float lrun[4];
#pragma unroll
    for (int hh = 0; hh < 4; ++hh) {
        o[hh] = (floatx4){0.f, 0.f, 0.f, 0.f};
        lrun[hh] = 0.f;
    }

    // lane-private bias stream base: bias[n0+qi][m0+4g + r][h0..h0+3]
    const float* bb = bias + ((size_t)(n0 + qi) * NSEQ + m0 + 4 * g) * HEADS + h0;

    f32x4 bufA[4], bufB[4];
    // prologue: own tile 0 (kt = par)
#pragma unroll
    for (int r = 0; r < 4; ++r)
        bufA[r] = *(const f32x4*)(bb + par * (16 * HEADS) + r * HEADS);

    auto body = [&](int i, f32x4* cur, f32x4* nxt) {
        const int kt = 2 * i + par;
        const int m1 = m0 + kt * 16;
        // extract C-init (frees cur's regs): s[hh][r] = bias[n0+qi][m1+4g+r][h0+hh]
        floatx4 s[4];
#pragma unroll
        for (int hh = 0; hh < 4; ++hh)
            s[hh] = (floatx4){cur[0][hh], cur[1][hh], cur[2][hh], cur[3][hh]};
        // issue next own tile's loads (1 tile ahead; consumed next body)
        if (i + 1 < OWN_T) {
            const float* bn = bb + (size_t)(2 * (i + 1) + par) * (16 * HEADS);
#pragma unroll
            for (int r = 0; r < 4; ++r) nxt[r] = *(const f32x4*)(bn + r * HEADS);
        }
        const uchar4 mk = *(const uchar4*)(mask + m1 + 4 * g);
#pragma unroll
        for (int hh = 0; hh < 4; ++hh) {
            const int h = h0 + hh;
            // K A-fragment: A[row=key=qi][dim 4g+i]
            short4v ka = *(const short4v*)((const ushort_t*)Kb +
                         (size_t)(m1 + qi) * HID + h * HD + 4 * g);
            // S^T = (K.Qh^T + K.Ql^T) + bias  (SCALE folded into Qh/Ql)
            floatx4 sv = __builtin_amdgcn_mfma_f32_16x16x16bf16_1k(ka, qhf[hh], s[hh], 0, 0, 0);
            sv = __builtin_amdgcn_mfma_f32_16x16x16bf16_1k(ka, qlf[hh], sv, 0, 0, 0);
            float e0 = mk.x ? 0.f : __expf(sv.x);
            float e1 = mk.y ? 0.f : __expf(sv.y);
            float e2 = mk.z ? 0.f : __expf(sv.z);
            float e3 = mk.w ? 0.f : __expf(sv.w);
            lrun[hh] += (e0 + e1) + (e2 + e3);
            // P A-fragment for PV (lane already holds P[q=qi][key=4g+r])
            __hip_bfloat16 p0 = __float2bfloat16(e0);
            __hip_bfloat16 p1 = __float2bfloat16(e1);
            __hip_bfloat16 p2 = __float2bfloat16(e2);
            __hip_bfloat16 p3 = __float2bfloat16(e3);
            short4v pa = {(short)*(ushort_t*)&p0, (short)*(ushort_t*)&p1,
                          (short)*(ushort_t*)&p2, (short)*(ushort_t*)&p3};
            // V B-fragment: B[k=key 4g+i][col=d=qi]
            short4v vb = *(const short4v*)((const ushort_t*)Vt +
                         (size_t)(h * HD + qi) * NSEQ + m1 + 4 * g);
            o[hh] = __builtin_amdgcn_mfma_f32_16x16x16bf16_1k(pa, vb, o[hh], 0, 0, 0);
        }
    };

#pragma unroll
    for (int i = 0; i < OWN_T; i += 2) {
        body(i, bufA, bufB);
        body(i + 1, bufB, bufA);
    }

    // ---- epilogue: merge kt-parity wave pairs, then store ----
#pragma unroll
    for (int hh = 0; hh < 4; ++hh) {
        lrun[hh] += __shfl_xor(lrun[hh], 16);  // sum over g
        lrun[hh] += __shfl_xor(lrun[hh], 32);
    }
    if (par == 1) {
#pragma unroll
        for (int hh = 0; hh < 4; ++hh) {
#pragma unroll
            for (int r = 0; r < 4; ++r) ob[wid & 1][hh * 4 + r][lane] = o[hh][r];
            if (g == 0) lr[wid & 1][hh][qi] = lrun[hh];
        }
    }
    __syncthreads();
    if (par == 0) {
#pragma unroll
        for (int hh = 0; hh < 4; ++hh) {
            const int h = h0 + hh;
#pragma unroll
            for (int r = 0; r < 4; ++r) {
                float v = o[hh][r] + ob[wid & 1][hh * 4 + r][lane];
                Op[((size_t)(n0 + 4 * g + r) * SPLIT + sp) * HID + h * HD + qi] = v;
            }
            if (g == 0) {
                float l = lrun[hh] + lr[wid & 1][hh][qi];
                Lp[((size_t)(n0 + qi) * SPLIT + sp) * HEADS + h] = l;
            }
        }
    }
}

// ---------------- kernel C: combine splits + output projection ----------------
// grid 512 blocks x 128 threads, 4 rows per block
__global__ __launch_bounds__(128) void proj_kernel(
    const float* __restrict__ Op, const float* __restrict__ Lp,
    const float* __restrict__ Wo, const float* __restrict__ bo,
    float* __restrict__ out)
{
    __shared__ float xs[4 * HID];
    const int j = threadIdx.x;
    const int r0 = blockIdx.x * 4;
    const int hh = j >> 4;
#pragma unroll
    for (int r = 0; r < 4; ++r) {
        const size_t n = r0 + r;
        float s = 0.f, l = 0.f;
#pragma unroll
        for (int sp = 0; sp < SPLIT; ++sp) {
            s += Op[(n * SPLIT + sp) * HID + j];
            l += Lp[(n * SPLIT + sp) * HEADS + hh];
        }
        xs[r * HID + j] = s / l;
    }
    __syncthreads();
    float acc[4];
#pragma unroll
    for (int r = 0; r < 4; ++r) acc[r] = 0.f;
    const float4* Wrow = (const float4*)(Wo + (size_t)j * HID);
#pragma unroll 4
    for (int i4 = 0; i4 < HID / 4; ++i4) {
        float4 wv = Wrow[i4];
#pragma unroll
        for (int r = 0; r < 4; ++r) {
            float4 xv = *(const float4*)&xs[r * HID + i4 * 4];
            acc[r] = fmaf(xv.x, wv.x, acc[r]);
            acc[r] = fmaf(xv.y, wv.y, acc[r]);
            acc[r] = fmaf(xv.z, wv.z, acc[r]);
            acc[r] = fmaf(xv.w, wv.w, acc[r]);
        }
    }
    float b = bo[j];
#pragma unroll
    for (int r = 0; r < 4; ++r)
        out[(size_t)(r0 + r) * HID + j] = acc[r] + b;
}

extern "C" void kernel_launch(void* const* d_in, const int* in_sizes, int n_in,
                              void* d_out, int out_size, void* d_ws, size_t ws_size,
                              hipStream_t stream) {
    const float* x    = (const float*)d_in[0];
    const float* bias = (const float*)d_in[1];
    const unsigned char* mask = (const unsigned char*)d_in[2];
    const float* Wq = (const float*)d_in[3];
    const float* bq = (const float*)d_in[4];
    const float* Wk = (const float*)d_in[5];
    const float* bk = (const float*)d_in[6];
    const float* Wv = (const float*)d_in[7];
    const float* bv = (const float*)d_in[8];
    const float* Wo = (const float*)d_in[9];
    const float* bo = (const float*)d_in[10];
    float* out = (float*)d_out;

    float* w = (float*)d_ws;
    // ws layout (float offsets):
    __hip_bfloat16* Qh = (__hip_bfloat16*)(w);           // 262144 bf16
    __hip_bfloat16* Ql = (__hip_bfloat16*)(w + 131072);  // 262144 bf16
    __hip_bfloat16* Kb = (__hip_bfloat16*)(w + 262144);  // 262144 bf16 rows [n][j]
    __hip_bfloat16* Vt = (__hip_bfloat16*)(w + 393216);  // 262144 bf16 TRANSPOSED [j][n]
    float* Op  = w + 524288;                             // NSEQ*SPLIT*HID fp32 (8 MB), [n][sp][hd]
    float* Lp  = w + 524288 + (size_t)NSEQ * SPLIT * HID; // [n][sp][h]
    // total ~11 MB

    qkv_kernel<<<768, 128, 0, stream>>>(x, Wq, Wk, Wv, bq, bk, bv, Qh, Ql, Kb, Vt);
    attn_kernel<<<128 * SPLIT, 256, 0, stream>>>(Qh, Ql, Kb, Vt, bias, mask, Op, Lp);
    proj_kernel<<<512, 128, 0, stream>>>(Op, Lp, Wo, bo, out);
}

// Round 7
// 237.803 us; speedup vs baseline: 1.0840x; 1.0840x over previous
//
#include <hip/hip_runtime.h>
#include <hip/hip_bf16.h>

#define NSEQ 2048
#define HID 128
#define HEADS 8
#define HD 16
#define SCALE 0.25f
#define SPLIT 8
#define KEYS_PER (NSEQ / SPLIT)   // 256 keys per block
#define NT (KEYS_PER / 16)        // 16 sixteen-key tiles
#define SB 132                    // bias LDS q-row stride in words ([h][m]=128 + 4 pad)
#define SKV 68                    // K/V LDS key-row stride in words (64 + 4 pad)

typedef unsigned short ushort_t;
typedef __attribute__((ext_vector_type(4))) short short4v;   // 4 bf16 (A/B frag, K=16 MFMA)
typedef __attribute__((ext_vector_type(4))) float floatx4;   // C/D frag
typedef __attribute__((ext_vector_type(4))) float f32x4;

// ---------------- kernel A: QKV projection ----------------
// grid 768 blocks x 128 threads; blocks [0,256)->Q (scaled bf16 hi/lo split),
// [256,512)->K bf16 rows, [512,768)->V bf16 rows (row-major Vm[n][j]).
__global__ __launch_bounds__(128) void qkv_kernel(
    const float* __restrict__ x, const float* __restrict__ Wq,
    const float* __restrict__ Wk, const float* __restrict__ Wv,
    const float* __restrict__ bq, const float* __restrict__ bk,
    const float* __restrict__ bv,
    __hip_bfloat16* __restrict__ Qh, __hip_bfloat16* __restrict__ Ql,
    __hip_bfloat16* __restrict__ Kb, __hip_bfloat16* __restrict__ Vm)
{
    __shared__ float xs[8 * HID];
    const int j = threadIdx.x;
    const int mat = blockIdx.x >> 8;
    const int rb = blockIdx.x & 255;
    const int r0 = rb * 8;
    const float* W = (mat == 0) ? Wq : (mat == 1) ? Wk : Wv;
    const float* bb = (mat == 0) ? bq : (mat == 1) ? bk : bv;
    const float4* xg = (const float4*)(x + (size_t)r0 * HID);
    float4* xl = (float4*)xs;
    for (int i = j; i < 8 * HID / 4; i += 128) xl[i] = xg[i];
    __syncthreads();
    float acc[8];
#pragma unroll
    for (int r = 0; r < 8; ++r) acc[r] = 0.f;
    const float4* Wrow = (const float4*)(W + (size_t)j * HID);
#pragma unroll 4
    for (int i4 = 0; i4 < HID / 4; ++i4) {
        float4 wv = Wrow[i4];
#pragma unroll
        for (int r = 0; r < 8; ++r) {
            float4 xv = *(const float4*)&xs[r * HID + i4 * 4];
            acc[r] = fmaf(xv.x, wv.x, acc[r]);
            acc[r] = fmaf(xv.y, wv.y, acc[r]);
            acc[r] = fmaf(xv.z, wv.z, acc[r]);
            acc[r] = fmaf(xv.w, wv.w, acc[r]);
        }
    }
    float bv_ = bb[j];
#pragma unroll
    for (int r = 0; r < 8; ++r) acc[r] += bv_;
    if (mat == 0) {
        // scaled hi/lo bf16 split: Qh + Ql represents acc*SCALE to ~2^-17 rel
#pragma unroll
        for (int r = 0; r < 8; ++r) {
            float qsv = acc[r] * SCALE;                 // exact (SCALE = 2^-2)
            __hip_bfloat16 hb = __float2bfloat16(qsv);
            float hf = __bfloat162float(hb);
            __hip_bfloat16 lb = __float2bfloat16(qsv - hf);
            Qh[(size_t)(r0 + r) * HID + j] = hb;
            Ql[(size_t)(r0 + r) * HID + j] = lb;
        }
    } else if (mat == 1) {
#pragma unroll
        for (int r = 0; r < 8; ++r) Kb[(size_t)(r0 + r) * HID + j] = __float2bfloat16(acc[r]);
    } else {
#pragma unroll
        for (int r = 0; r < 8; ++r) Vm[(size_t)(r0 + r) * HID + j] = __float2bfloat16(acc[r]);
    }
}

// ---------------- kernel B: fused attention, dense-load LDS-staged ----------------
// grid 1024 blocks x 256 threads (4 waves; wave = 2 heads x 16 q-rows x all keys).
// ALL global loads are fully coalesced (16B/lane contiguous): bias tile 16x512B
// (2 instr/tile), K tile 16x256B (1 instr), V tile 16x256B (1 instr).
// Redistribution via double-buffered LDS, one barrier per tile, prefetch-1.
// S^T = K.Q^T via mfma_16x16x16_bf16, C preloaded with bias (ds_read_b128);
// S^T C-layout (lane holds P[key=4g+r][q=qi]) IS the A-frag layout for PV mfma.
__global__ __launch_bounds__(256, 4) void attn_kernel(
    const __hip_bfloat16* __restrict__ Qh, const __hip_bfloat16* __restrict__ Ql,
    const __hip_bfloat16* __restrict__ Kb, const __hip_bfloat16* __restrict__ Vm,
    const float* __restrict__ bias, const unsigned char* __restrict__ mask,
    float* __restrict__ Op, float* __restrict__ Lp)
{
    __shared__ float bsh[2][16 * SB];    // 16.9 KB bias [q][h][m]
    __shared__ float ksh[2][16 * SKV];   // 8.7 KB  K    [key][dim words]
    __shared__ float vsh[2][16 * SKV];   // 8.7 KB  V    [key][j words]

    const int t = threadIdx.x;
    const int lane = t & 63;
    const int wid = t >> 6;
    const int qi = lane & 15;          // q row (scores) / d col (PV out)
    const int g = lane >> 4;           // 0..3
    const int h0 = wid * 2;            // this wave's 2 heads

    const int qb = blockIdx.x & 127;
    const int sp = blockIdx.x >> 7;
    const int n0 = qb * 16;
    const int m0 = sp * KEYS_PER;

    // dense staging roles
    const int bq = t >> 5;             // 0..7  (bias rows, 2 instrs cover 16)
    const int bc = t & 31;             // 0..31 (16B chunk within 512B row)
    const int kq = t >> 4;             // 0..15 (K/V key row)
    const int kc = t & 15;             // 0..15 (16B chunk within 256B row)

    const float* bA = bias + ((size_t)(n0 + bq) * NSEQ + m0) * HEADS + bc * 4;
    const float* bB = bias + ((size_t)(n0 + 8 + bq) * NSEQ + m0) * HEADS + bc * 4;
    const ushort_t* kG = (const ushort_t*)Kb + (size_t)(m0 + kq) * HID + kc * 8;
    const ushort_t* vG = (const ushort_t*)Vm + (size_t)(m0 + kq) * HID + kc * 8;

    // bias LDS write decomposition: chunk bc = floats {4bc..4bc+3} of [m][h] row
    // -> m = bc>>1, h = 4*(bc&1)+k  =>  word q*SB + h*16 + m
    const int bm = bc >> 1;
    const int bh = 4 * (bc & 1);
    const int wA = bq * SB + bh * 16 + bm;
    const int wB = (8 + bq) * SB + bh * 16 + bm;
    const int wK = kq * SKV + kc * 4;

    // Q B-fragments for 2 heads (hi/lo): B[k=dim 4g+i][col=q=qi]
    short4v qhf[2], qlf[2];
#pragma unroll
    for (int hh = 0; hh < 2; ++hh) {
        const size_t qoff = (size_t)(n0 + qi) * HID + (h0 + hh) * HD + 4 * g;
        qhf[hh] = *(const short4v*)((const ushort_t*)Qh + qoff);
        qlf[hh] = *(const short4v*)((const ushort_t*)Ql + qoff);
    }

    floatx4 o[2];
    o[0] = (floatx4){0.f, 0.f, 0.f, 0.f};
    o[1] = (floatx4){0.f, 0.f, 0.f, 0.f};
    float lrun[2] = {0.f, 0.f};

    // prologue: tile 0 staged into regs
    f32x4 sb0 = *(const f32x4*)bA;
    f32x4 sb1 = *(const f32x4*)bB;
    f32x4 sk  = *(const f32x4*)kG;
    f32x4 sv  = *(const f32x4*)vG;

    for (int kt = 0; kt < NT; ++kt) {
        float* Bs = &bsh[kt & 1][0];
        float* Ks = &ksh[kt & 1][0];
        float* Vs = &vsh[kt & 1][0];
        // scatter staged tile into LDS (2-way banks = free)
        Bs[wA]      = sb0.x; Bs[wA + 16] = sb0.y;
        Bs[wA + 32] = sb0.z; Bs[wA + 48] = sb0.w;
        Bs[wB]      = sb1.x; Bs[wB + 16] = sb1.y;
        Bs[wB + 32] = sb1.z; Bs[wB + 48] = sb1.w;
        *(f32x4*)&Ks[wK] = sk;
        *(f32x4*)&Vs[wK] = sv;
        __syncthreads();
        // prefetch next tile (lands during this tile's compute + next barrier)
        if (kt + 1 < NT) {
            sb0 = *(const f32x4*)(bA + (kt + 1) * (16 * HEADS));
            sb1 = *(const f32x4*)(bB + (kt + 1) * (16 * HEADS));
            sk  = *(const f32x4*)(kG + (size_t)(kt + 1) * 16 * HID);
            sv  = *(const f32x4*)(vG + (size_t)(kt + 1) * 16 * HID);
        }
        const int m1 = m0 + kt * 16;
        const uchar4 mk = *(const uchar4*)(mask + m1 + 4 * g);
        const ushort_t* vw = (const ushort_t*)Vs;
#pragma unroll
        for (int hh = 0; hh < 2; ++hh) {
            const int h = h0 + hh;
            // C init: b128 -> bias[n0+qi][m1+4g+r][h], conflict-free
            floatx4 s = *(const f32x4*)&Bs[qi * SB + h * 16 + 4 * g];
            // K A-fragment: b64 -> K[m1+qi][h*16+4g..+3], conflict-free
            short4v ka = *(const short4v*)&Ks[qi * SKV + h * 8 + 2 * g];
            // S^T = (K.Qh^T + K.Ql^T) + bias  (SCALE folded into Qh/Ql)
            s = __builtin_amdgcn_mfma_f32_16x16x16bf16_1k(ka, qhf[hh], s, 0, 0, 0);
            s = __builtin_amdgcn_mfma_f32_16x16x16bf16_1k(ka, qlf[hh], s, 0, 0, 0);
            float e0 = mk.x ? 0.f : __expf(s.x);
            float e1 = mk.y ? 0.f : __expf(s.y);
            float e2 = mk.z ? 0.f : __expf(s.z);
            float e3 = mk.w ? 0.f : __expf(s.w);
            lrun[hh] += (e0 + e1) + (e2 + e3);
            // P A-fragment for PV (lane already holds P[q=qi][key=4g+r])
            __hip_bfloat16 p0 = __float2bfloat16(e0);
            __hip_bfloat16 p1 = __float2bfloat16(e1);
            __hip_bfloat16 p2 = __float2bfloat16(e2);
            __hip_bfloat16 p3 = __float2bfloat16(e3);
            short4v pa = {(short)*(ushort_t*)&p0, (short)*(ushort_t*)&p1,
                          (short)*(ushort_t*)&p2, (short)*(ushort_t*)&p3};
            // V B-fragment: 4x ds_read_u16 (broadcast pairs, conflict-free):
            // B[k=key 4g+i][col=d=qi] = V[m1+4g+i][h*16+qi]
            ushort_t e0v = vw[(4 * g + 0) * (2 * SKV) + h * 16 + qi];
            ushort_t e1v = vw[(4 * g + 1) * (2 * SKV) + h * 16 + qi];
            ushort_t e2v = vw[(4 * g + 2) * (2 * SKV) + h * 16 + qi];
            ushort_t e3v = vw[(4 * g + 3) * (2 * SKV) + h * 16 + qi];
            short4v vb = {(short)e0v, (short)e1v, (short)e2v, (short)e3v};
            o[hh] = __builtin_amdgcn_mfma_f32_16x16x16bf16_1k(pa, vb, o[hh], 0, 0, 0);
        }
        // next iter writes the OTHER buffer; this buffer is only rewritten at
        // kt+2, after the barrier at kt+1 has ordered all reads above.
    }

    // ---- epilogue: O partials (lane holds O[q=4g+r][d=qi]) + l partials ----
#pragma unroll
    for (int hh = 0; hh < 2; ++hh) {
        lrun[hh] += __shfl_xor(lrun[hh], 16);  // sum over g
        lrun[hh] += __shfl_xor(lrun[hh], 32);
        const int h = h0 + hh;
#pragma unroll
        for (int r = 0; r < 4; ++r)
            Op[((size_t)(n0 + 4 * g + r) * SPLIT + sp) * HID + h * HD + qi] = o[hh][r];
        if (g == 0)
            Lp[((size_t)(n0 + qi) * SPLIT + sp) * HEADS + h] = lrun[hh];
    }
}

// ---------------- kernel C: combine splits + output projection ----------------
// grid 512 blocks x 128 threads, 4 rows per block
__global__ __launch_bounds__(128) void proj_kernel(
    const float* __restrict__ Op, const float* __restrict__ Lp,
    const float* __restrict__ Wo, const float* __restrict__ bo,
    float* __restrict__ out)
{
    __shared__ float xs[4 * HID];
    const int j = threadIdx.x;
    const int r0 = blockIdx.x * 4;
    const int hh = j >> 4;
#pragma unroll
    for (int r = 0; r < 4; ++r) {
        const size_t n = r0 + r;
        float s = 0.f, l = 0.f;
#pragma unroll
        for (int sp = 0; sp < SPLIT; ++sp) {
            s += Op[(n * SPLIT + sp) * HID + j];
            l += Lp[(n * SPLIT + sp) * HEADS + hh];
        }
        xs[r * HID + j] = s / l;
    }
    __syncthreads();
    float acc[4];
#pragma unroll
    for (int r = 0; r < 4; ++r) acc[r] = 0.f;
    const float4* Wrow = (const float4*)(Wo + (size_t)j * HID);
#pragma unroll 4
    for (int i4 = 0; i4 < HID / 4; ++i4) {
        float4 wv = Wrow[i4];
#pragma unroll
        for (int r = 0; r < 4; ++r) {
            float4 xv = *(const float4*)&xs[r * HID + i4 * 4];
            acc[r] = fmaf(xv.x, wv.x, acc[r]);
            acc[r] = fmaf(xv.y, wv.y, acc[r]);
            acc[r] = fmaf(xv.z, wv.z, acc[r]);
            acc[r] = fmaf(xv.w, wv.w, acc[r]);
        }
    }
    float b = bo[j];
#pragma unroll
    for (int r = 0; r < 4; ++r)
        out[(size_t)(r0 + r) * HID + j] = acc[r] + b;
}

extern "C" void kernel_launch(void* const* d_in, const int* in_sizes, int n_in,
                              void* d_out, int out_size, void* d_ws, size_t ws_size,
                              hipStream_t stream) {
    const float* x    = (const float*)d_in[0];
    const float* bias = (const float*)d_in[1];
    const unsigned char* mask = (const unsigned char*)d_in[2];
    const float* Wq = (const float*)d_in[3];
    const float* bq = (const float*)d_in[4];
    const float* Wk = (const float*)d_in[5];
    const float* bk = (const float*)d_in[6];
    const float* Wv = (const float*)d_in[7];
    const float* bv = (const float*)d_in[8];
    const float* Wo = (const float*)d_in[9];
    const float* bo = (const float*)d_in[10];
    float* out = (float*)d_out;

    float* w = (float*)d_ws;
    // ws layout (float offsets):
    __hip_bfloat16* Qh = (__hip_bfloat16*)(w);           // 262144 bf16
    __hip_bfloat16* Ql = (__hip_bfloat16*)(w + 131072);  // 262144 bf16
    __hip_bfloat16* Kb = (__hip_bfloat16*)(w + 262144);  // 262144 bf16 rows [n][j]
    __hip_bfloat16* Vm = (__hip_bfloat16*)(w + 393216);  // 262144 bf16 rows [n][j]
    float* Op  = w + 524288;                             // NSEQ*SPLIT*HID fp32 (8 MB), [n][sp][hd]
    float* Lp  = w + 524288 + (size_t)NSEQ * SPLIT * HID; // [n][sp][h]
    // total ~11 MB

    qkv_kernel<<<768, 128, 0, stream>>>(x, Wq, Wk, Wv, bq, bk, bv, Qh, Ql, Kb, Vm);
    attn_kernel<<<128 * SPLIT, 256, 0, stream>>>(Qh, Ql, Kb, Vm, bias, mask, Op, Lp);
    proj_kernel<<<512, 128, 0, stream>>>(Op, Lp, Wo, bo, out);
}